// Round 3
// baseline (465.768 us; speedup 1.0000x reference)
//
#include <hip/hip_runtime.h>
#include <cstdint>
#include <cstddef>

typedef unsigned short u16;
typedef __attribute__((ext_vector_type(8))) short short8;    // 8 bf16 (4 VGPR)
typedef __attribute__((ext_vector_type(16))) float f32x16;   // 32x32 MFMA C/D
typedef __attribute__((ext_vector_type(4))) int i32x4;

constexpr int M  = 8192;
constexpr int Nn = 4096;
constexpr int K1 = 2048;
constexpr int K2 = 4096;
constexpr int K  = K1 + K2;            // 6144
constexpr int BM = 256, BN = 256;
constexpr int NKT = K / 64;            // 96 K-tiles of BK=64
constexpr float LEAK = 0.3f;

__device__ __forceinline__ u16 f2bf(float f) {
  unsigned u = __float_as_uint(f);
  u += 0x7FFFu + ((u >> 16) & 1u);     // RNE
  return (u16)(u >> 16);
}

template<int C1, int C2>
__global__ void cast_concat(const float* __restrict__ X, const float* __restrict__ S,
                            u16* __restrict__ out, int rows)
{
  constexpr int C = C1 + C2;
  const size_t total = (size_t)rows * C / 8;
  for (size_t i = blockIdx.x * (size_t)blockDim.x + threadIdx.x; i < total;
       i += (size_t)gridDim.x * blockDim.x) {
    const size_t e = i * 8;
    const int r = (int)(e / C);
    const int c = (int)(e - (size_t)r * C);
    const float* src = (c < C1) ? (X + (size_t)r * C1 + c)
                                : (S + (size_t)r * C2 + (c - C1));
    const float4* s4 = (const float4*)src;
    float4 f0 = s4[0], f1 = s4[1];
    alignas(16) u16 tmp[8];
    tmp[0] = f2bf(f0.x); tmp[1] = f2bf(f0.y); tmp[2] = f2bf(f0.z); tmp[3] = f2bf(f0.w);
    tmp[4] = f2bf(f1.x); tmp[5] = f2bf(f1.y); tmp[6] = f2bf(f1.z); tmp[7] = f2bf(f1.w);
    *(i32x4*)(out + e) = *(i32x4*)tmp;
  }
}

__device__ __forceinline__ void gload16(const u16* g, u16* l) {
  __builtin_amdgcn_global_load_lds(
      (const __attribute__((address_space(1))) void*)g,
      (__attribute__((address_space(3))) void*)l, 16, 0, 0);
}

__device__ __forceinline__ float fast_tanh(float x) {
  const float ax = __builtin_fabsf(x);
  const float e  = __builtin_amdgcn_exp2f(ax * 2.8853900817779268f); // 2*log2(e)
  const float r  = 1.0f - 2.0f * __builtin_amdgcn_rcpf(e + 1.0f);
  return __builtin_copysignf(r, x);
}

#define BAR()   __builtin_amdgcn_s_barrier()
#define LGKM0() asm volatile("s_waitcnt lgkmcnt(0)" ::: "memory")
#define LGKM4() asm volatile("s_waitcnt lgkmcnt(4)" ::: "memory")
#define LGKM8() asm volatile("s_waitcnt lgkmcnt(8)" ::: "memory")
#define VMW8()  asm volatile("s_waitcnt vmcnt(8)" ::: "memory")
#define VMW0()  asm volatile("s_waitcnt vmcnt(0)" ::: "memory")
#define SB0()   __builtin_amdgcn_sched_barrier(0)

// 256x256 tile, BK=64, 8 waves (128x64/wave), 32x32x16 MFMA (2495 TF ceiling
// vs 2075 for 16x16x32; 8 MFMA/phase/wave). 8-phase/2-K-tile schedule, one
// barrier per phase, frag reads ONE PHASE AHEAD (double-buffered afE/afO,
// bfE/bfO), counted lgkm waits retire the current phase's operands while the
// next phase's reads drain under the MFMA cluster.
// DEEP STAGING (m218 counted-vmcnt regime): full-tile 4-load bursts at each
// buffer's earliest writable phase; only TWO vmcnt waits per iteration:
//   ph3: stg B(T+2)->B0   (B0 last read ph1, retired ph2-LGKM8 + bar)
//   ph4: stg A(T+2)->A0   (A0 last read ph2, retired ph3-LGKM8 + bar)
//   ph7: stg B(T+3)->B1   (B1 last read ph5, retired ph6-LGKM8 + bar)
//   ph8: stg A(T+3)->A1   (A1 last read ph6, retired ph7-LGKM8 + bar)
// VMW0 at ph2-end: drains prev-ph7/ph8 (A(T+1),B(T+1)) -- 2-3 phase gap --
//   before ph3/ph4 read them. VMW0 at ph6-end: drains ph3/ph4 (B(T+2),
//   A(T+2)) before ph7/ph8 read them. Nothing newer is in flight at either
//   point, so these are cheap drains of >=2-phase-old loads (HBM ~900 cyc
//   fully covered).
// Frag layout (32x32x16): A row=lane&31, k-slot=(ks*2+(lane>>5)) 8-el groups;
// phys slot = logical ^ (row&7), row&7==lane&7. C/D: col=lane&31,
// row=(reg&3)+8*(reg>>2)+4*(lane>>5).
__global__ __launch_bounds__(512, 2) void gemm_fused(
    const u16* __restrict__ A,      // [M][K] bf16
    const u16* __restrict__ W,      // [N][K] bf16
    const float* __restrict__ prev, // [M][N] fp32
    float* __restrict__ out)        // [M][N] fp32
{
  __shared__ u16 lds[65536];        // 128 KiB: A0@0 A1@16384 B0@32768 B1@49152

  const int tid  = threadIdx.x;
  const int lane = tid & 63;
  const int wid  = tid >> 6;
  const int wr   = wid >> 2;        // 0..1 -> 128-row half of C
  const int wc   = wid & 3;         // 0..3 -> 64-col quarter of C

  // XCD-aware bijective swizzle (512 % 8 == 0)
  const int cpx = gridDim.x >> 3;
  const int wg  = ((int)blockIdx.x & 7) * cpx + ((int)blockIdx.x >> 3);
  const int bn  = wg & 15;          // Nn/BN = 16
  const int bm  = wg >> 4;          // M/BM  = 32

  // staging: one gload16 sweep = 64 rows x 64 cols; stg() = rows r, r+64
  const int sr = tid >> 3;          // 0..63
  const int ss = (tid & 7) ^ (sr & 7);   // inverse swizzle on global source
  const u16* pA = A + (size_t)(bm * BM + sr) * K + ss * 8;
  const u16* pW = W + (size_t)(bn * BN + sr) * K + ss * 8;
  u16* ldsw = lds + wid * 512;
  const size_t rowK64  = (size_t)64  * K;
  const size_t rowK128 = (size_t)128 * K;

  auto stg = [&](const u16* g, int dst) {
    gload16(g,          ldsw + dst);
    gload16(g + rowK64, ldsw + dst + 4096);
  };

  // fragment read addressing: row*64 + (slot^(lane&7))*8, slot = ks*2+(lane>>5)
  const int l31 = lane & 31, l5 = lane >> 5, l7 = lane & 7;
  int aoffk[4], boffk[4];
  #pragma unroll
  for (int ks = 0; ks < 4; ++ks) {
    const int sk = (ks * 2 + l5) ^ l7;
    aoffk[ks] = (wr * 128 + l31) * 64 + sk * 8;
    boffk[ks] = (wc * 64  + l31) * 64 + sk * 8;
  }

  short8 afE[2][4], afO[2][4];      // A frags: 2 mt-locals x 4 ks
  short8 bfE[4],    bfO[4];         // B frags: 4 ks
  f32x16 acc[4][2];
  #pragma unroll
  for (int mt = 0; mt < 4; ++mt)
    #pragma unroll
    for (int ng = 0; ng < 2; ++ng) acc[mt][ng] = (f32x16)0.f;

  auto dsA = [&](short8 (&Av)[2][4], int mg, int ab) {   // 8 ds_read_b128
    #pragma unroll
    for (int mtl = 0; mtl < 2; ++mtl)
      #pragma unroll
      for (int ks = 0; ks < 4; ++ks)
        Av[mtl][ks] = *(const short8*)(lds + ab + mg * 4096 + mtl * 2048 + aoffk[ks]);
  };
  auto dsB = [&](short8 (&Bv)[4], int ng, int bb) {      // 4 ds_read_b128
    #pragma unroll
    for (int ks = 0; ks < 4; ++ks)
      Bv[ks] = *(const short8*)(lds + bb + ng * 2048 + boffk[ks]);
  };
  auto MM = [&](short8 (&Av)[2][4], short8 (&Bv)[4], int mg, int ng) {  // 8 MFMA
    __builtin_amdgcn_s_setprio(1);
    #pragma unroll
    for (int ks = 0; ks < 4; ++ks)
      #pragma unroll
      for (int mtl = 0; mtl < 2; ++mtl)
        acc[mg * 2 + mtl][ng] = __builtin_amdgcn_mfma_f32_32x32x16_bf16(
            Av[mtl][ks], Bv[ks], acc[mg * 2 + mtl][ng], 0, 0, 0);
    __builtin_amdgcn_s_setprio(0);
  };

  // ---- prologue: B(0),A(0),B(1),A(1) full tiles (16 loads); tile0 must land
  stg(pW,                 32768); stg(pW + rowK128,      32768 + 8192);
  stg(pA,                 0);     stg(pA + rowK128,      8192);
  stg(pW + 64,            49152); stg(pW + 64 + rowK128, 49152 + 8192);
  stg(pA + 64,            16384); stg(pA + 64 + rowK128, 16384 + 8192);
  VMW8();                         // B(0),A(0) landed; tile1 drains by ph2
  BAR();
  dsA(afE, 0, 0);                 // tile0 mg0
  dsB(bfE, 0, 32768);             // tile0 ng0

  const u16* gA = pA;
  const u16* gW = pW;
  #pragma unroll 1
  for (int i = 0; i < 47; ++i) {  // tiles T=2i (buf0), T+1 (buf1); stages T+2,T+3
    // ph1
    dsB(bfO, 1, 32768);
    LGKM4(); SB0(); MM(afE, bfE, 0, 0); BAR();
    // ph2
    dsA(afO, 1, 0);
    LGKM8(); SB0(); MM(afE, bfO, 0, 1); VMW0(); BAR();
    // ph3: B0 free -> stage B(T+2) full
    dsA(afE, 0, 16384);
    stg(gW + 128, 32768); stg(gW + 128 + rowK128, 32768 + 8192);
    LGKM8(); SB0(); MM(afO, bfE, 1, 0); BAR();
    // ph4: A0 free -> stage A(T+2) full
    dsB(bfE, 0, 49152);
    stg(gA + 128, 0); stg(gA + 128 + rowK128, 8192);
    SB0(); MM(afO, bfO, 1, 1); BAR();
    // ph5
    dsB(bfO, 1, 49152);
    LGKM4(); SB0(); MM(afE, bfE, 0, 0); BAR();
    // ph6
    dsA(afO, 1, 16384);
    LGKM8(); SB0(); MM(afE, bfO, 0, 1); VMW0(); BAR();
    // ph7: B1 free -> stage B(T+3) full
    dsA(afE, 0, 0);
    stg(gW + 192, 49152); stg(gW + 192 + rowK128, 49152 + 8192);
    LGKM8(); SB0(); MM(afO, bfE, 1, 0); BAR();
    // ph8: A1 free -> stage A(T+3) full
    dsB(bfE, 0, 32768);
    stg(gA + 192, 16384); stg(gA + 192 + rowK128, 16384 + 8192);
    SB0(); MM(afO, bfO, 1, 1); BAR();
    gA += 128; gW += 128;
  }

  // ---- tail: tiles 94 (A0,B0), 95 (A1,B1); nothing left to stage
  dsB(bfO, 1, 32768);
  LGKM4(); SB0(); MM(afE, bfE, 0, 0); BAR();
  dsA(afO, 1, 0);
  LGKM8(); SB0(); MM(afE, bfO, 0, 1); VMW0(); BAR();
  dsA(afE, 0, 16384);
  LGKM8(); SB0(); MM(afO, bfE, 1, 0); BAR();
  dsB(bfE, 0, 49152);
  SB0(); MM(afO, bfO, 1, 1); BAR();
  dsB(bfO, 1, 49152);
  LGKM4(); SB0(); MM(afE, bfE, 0, 0); BAR();
  dsA(afO, 1, 16384);
  LGKM8(); SB0(); MM(afE, bfO, 0, 1); BAR();
  LGKM0(); SB0(); MM(afO, bfE, 1, 0);
  MM(afO, bfO, 1, 1);

  // ---- epilogue: 32x32 C/D: col=lane&31, row=(j&3)+8*(j>>2)+4*(lane>>5)
  const int crow0 = bm * BM + wr * 128 + l5 * 4;
  const int ccol0 = bn * BN + wc * 64 + l31;
  #pragma unroll
  for (int mt = 0; mt < 4; ++mt)
    #pragma unroll
    for (int ng = 0; ng < 2; ++ng)
      #pragma unroll
      for (int j = 0; j < 16; ++j) {
        const int row = crow0 + mt * 32 + (j & 3) + 8 * (j >> 2);
        const size_t off = (size_t)row * Nn + ccol0 + ng * 32;
        out[off] = (1.0f - LEAK) * prev[off] + LEAK * fast_tanh(acc[mt][ng][j]);
      }
}

extern "C" void kernel_launch(void* const* d_in, const int* in_sizes, int n_in,
                              void* d_out, int out_size, void* d_ws, size_t ws_size,
                              hipStream_t stream) {
  const float* inputs = (const float*)d_in[0];  // [8192][2048]
  const float* prev   = (const float*)d_in[1];  // [8192][4096]
  const float* w_in   = (const float*)d_in[2];  // [4096][2048]
  const float* w_res  = (const float*)d_in[3];  // [4096][4096]
  float* out = (float*)d_out;                   // [8192][4096]

  u16* Acat = (u16*)d_ws;                        // [M][K] bf16
  u16* Wcat = Acat + (size_t)M * K;              // [N][K] bf16

  cast_concat<K1, K2><<<2048, 256, 0, stream>>>(inputs, prev, Acat, M);
  cast_concat<K1, K2><<<1024, 256, 0, stream>>>(w_in, w_res, Wcat, Nn);

  gemm_fused<<<(M / BM) * (Nn / BN), 512, 0, stream>>>(Acat, Wcat, prev, out);
}